// Round 4
// baseline (356.975 us; speedup 1.0000x reference)
//
#include <hip/hip_runtime.h>

// Hidden-size-1 LSTM, B=32768 chains, 1024 open + 512 closed steps.
// FOUR LANES PER CHAIN: lane j of each quad owns gate j (i,f,g,o).
// Per step: each lane does 1 fma + ex2 + add + rcp for its gate, then
// 4 DPP quad_perm broadcasts give all lanes all four activations and
// every lane redundantly computes the short c/h tail (no selects).
// 2048 waves (16 chains each) -> 2 waves per SIMD on all 256 CUs.
// c kept pre-scaled: C = 2*log2(e)*c, so tanh(c) = 1 - 2*rcp(1+exp2(C)).
// sigma(z) = rcp(1+exp2(-L2E*z)); tanh(z) = 1 - 2*rcp(1+exp2(2*L2E*z)).

#define L2E 1.44269504088896340736f
#define B_TOT 32768
#define T_IN 1024
#define STEPS 512
#define CPB 16          // chains per block (one wave, 4 lanes/chain)
#define CH 64           // chunk length in steps
#define PAD 68          // LDS row stride in floats: 272B = 16B-aligned rows

__device__ __forceinline__ float ex2(float x){ return __builtin_amdgcn_exp2f(x); }
__device__ __forceinline__ float rcp(float x){ return __builtin_amdgcn_rcpf(x); }

template<int CTRL>
__device__ __forceinline__ float qperm(float v){
    return __int_as_float(__builtin_amdgcn_mov_dpp(__float_as_int(v), CTRL, 0xF, 0xF, true));
}

// z: this lane's gate pre-activation (scale already folded per lane).
__device__ __forceinline__ void lstm_tail(float z, float& h, float& C){
    float r  = rcp(1.0f + ex2(z));
    float ri = qperm<0x00>(r);   // lane0's value: sigma(zi)
    float rf = qperm<0x55>(r);   // lane1's: sigma(zf)
    float rg = qperm<0xAA>(r);   // lane2's: 1/(1+e^{2 zg_raw})
    float ro = qperm<0xFF>(r);   // lane3's: sigma(zo)
    float g2 = fmaf(rg, -4.0f * L2E, 2.0f * L2E);   // 2*L2E*tanh(g)
    C = fmaf(rf, C, ri * g2);                        // C = 2*L2E*c_new
    float rc = rcp(1.0f + ex2(C));
    float u  = rc + rc;
    h = fmaf(-u, ro, ro);                            // h = ro*(1-2rc)
}

// stage a 16-row x 64-col chunk: 4 float4 per lane, coalesced global reads
__device__ __forceinline__ void stage_issue16(const float* __restrict__ base,
                                              int rs, int col0, int lane, float4* v){
    const int r_lo = lane >> 4, c4 = lane & 15;
    #pragma unroll
    for (int j = 0; j < 4; ++j)
        v[j] = *(const float4*)(base + (size_t)(j*4 + r_lo) * rs + col0 + c4*4);
}
__device__ __forceinline__ void stage_write16(float* __restrict__ lds, int lane,
                                              const float4* v){
    const int r_lo = lane >> 4, c4 = lane & 15;
    #pragma unroll
    for (int j = 0; j < 4; ++j)
        *(float4*)(lds + (j*4 + r_lo) * PAD + c4*4) = v[j];
}

__global__ __launch_bounds__(64) void lstm_chain_kernel(
    const float* __restrict__ x, const float* __restrict__ t,
    const float* __restrict__ h0, const float* __restrict__ c0,
    const float* __restrict__ w_ih, const float* __restrict__ w_hh,
    const float* __restrict__ b_ih, const float* __restrict__ b_hh,
    float* __restrict__ out)
{
    __shared__ float sb[2][CPB * PAD];   // x/t staging, double-buffered
    __shared__ float pb[CPB * PAD];      // pred staging

    const int lane = threadIdx.x;
    const int g    = lane & 3;           // gate index: 0=i 1=f 2=g 3=o
    const int ch   = lane >> 2;          // chain within block (0..15)
    const int b0   = blockIdx.x * CPB;

    // per-lane gate constants (scale folded: -L2E for i,f,o; +2*L2E for g)
    float sc = (g == 2) ? (2.0f * L2E) : (-L2E);
    float A  = sc * w_ih[g];
    float Bh = sc * w_hh[g];
    float Cb = sc * (b_ih[g] + b_hh[g]);
    float W  = A + Bh;                   // closed loop: x_in = h

    float h = h0[b0 + ch];
    float C = (2.0f * L2E) * c0[b0 + ch];

    const float* xbase = x + (size_t)b0 * T_IN;
    const float* tbase = t + (size_t)b0 * STEPS;

    // ---- open loop: 16 chunks of 64 steps ----
    { float4 stg[4]; stage_issue16(xbase, T_IN, 0, lane, stg); stage_write16(sb[0], lane, stg); }
    #pragma unroll 1
    for (int k = 0; k < T_IN / CH; ++k){
        float4 stg[4];
        if (k < T_IN/CH - 1) stage_issue16(xbase, T_IN, (k+1)*CH, lane, stg);
        __syncthreads();   // sb[k&1] writes visible; prev reads of other buf done
        const float4* xrow = (const float4*)(&sb[k & 1][ch * PAD]);
        #pragma unroll 4
        for (int s4 = 0; s4 < CH/4; ++s4){
            float4 xq = xrow[s4];                       // quad-broadcast b128
            float zx0 = fmaf(xq.x, A, Cb);              // off critical path
            float zx1 = fmaf(xq.y, A, Cb);
            float zx2 = fmaf(xq.z, A, Cb);
            float zx3 = fmaf(xq.w, A, Cb);
            lstm_tail(fmaf(h, Bh, zx0), h, C);
            lstm_tail(fmaf(h, Bh, zx1), h, C);
            lstm_tail(fmaf(h, Bh, zx2), h, C);
            lstm_tail(fmaf(h, Bh, zx3), h, C);
        }
        if (k < T_IN/CH - 1) stage_write16(sb[(k+1) & 1], lane, stg);
    }
    float xin = sb[(T_IN/CH - 1) & 1][ch * PAD + (CH - 1)];  // x[b,1023]

    // ---- closed loop: 8 chunks of 64 steps ----
    { float4 stg[4]; stage_issue16(tbase, STEPS, 0, lane, stg); stage_write16(sb[0], lane, stg); }
    float lacc = 0.0f;
    #pragma unroll 1
    for (int k = 0; k < STEPS / CH; ++k){
        float4 stg[4];
        if (k < STEPS/CH - 1) stage_issue16(tbase, STEPS, (k+1)*CH, lane, stg);
        __syncthreads();   // sb[k&1] staged; prev flush reads of pb done
        const float4* trow = (const float4*)(&sb[k & 1][ch * PAD]);
        #pragma unroll 2
        for (int s4 = 0; s4 < CH/4; ++s4){
            float4 tq = trow[s4];
            float p0, p1, p2, p3, d;
            if (k == 0 && s4 == 0)
                lstm_tail(fmaf(xin, A, fmaf(h, Bh, Cb)), h, C);  // first closed step
            else
                lstm_tail(fmaf(h, W, Cb), h, C);
            p0 = h; d = h - tq.x; lacc = fmaf(d, d, lacc);
            lstm_tail(fmaf(h, W, Cb), h, C);
            p1 = h; d = h - tq.y; lacc = fmaf(d, d, lacc);
            lstm_tail(fmaf(h, W, Cb), h, C);
            p2 = h; d = h - tq.z; lacc = fmaf(d, d, lacc);
            lstm_tail(fmaf(h, W, Cb), h, C);
            p3 = h; d = h - tq.w; lacc = fmaf(d, d, lacc);
            if (g == 0)
                *(float4*)(&pb[ch * PAD + s4 * 4]) = make_float4(p0, p1, p2, p3);
        }
        __syncthreads();   // pb writes visible to all lanes
        // flush preds: 16 rows, 64 consecutive dwords per store instruction
        float* obase = out + 1 + (size_t)b0 * STEPS + k * CH;
        #pragma unroll 4
        for (int r = 0; r < CPB; ++r)
            obase[(size_t)r * STEPS + lane] = pb[r * PAD + lane];
        if (k < STEPS/CH - 1) stage_write16(sb[(k+1) & 1], lane, stg);
    }

    // ---- loss: each chain counted 4x (quad-redundant) -> scale by 0.25 ----
    #pragma unroll
    for (int off = 32; off > 0; off >>= 1)
        lacc += __shfl_down(lacc, off, 64);
    if (lane == 0)
        atomicAdd(out, lacc * (0.25f / (float)B_TOT));
}

extern "C" void kernel_launch(void* const* d_in, const int* in_sizes, int n_in,
                              void* d_out, int out_size, void* d_ws, size_t ws_size,
                              hipStream_t stream) {
    const float* x    = (const float*)d_in[0];
    const float* t    = (const float*)d_in[1];
    const float* h0   = (const float*)d_in[2];
    const float* c0   = (const float*)d_in[3];
    const float* w_ih = (const float*)d_in[4];
    const float* w_hh = (const float*)d_in[5];
    const float* b_ih = (const float*)d_in[6];
    const float* b_hh = (const float*)d_in[7];
    float* out = (float*)d_out;

    hipMemsetAsync(out, 0, sizeof(float), stream);

    lstm_chain_kernel<<<B_TOT / CPB, 64, 0, stream>>>(
        x, t, h0, c0, w_ih, w_hh, b_ih, b_hh, out);
}